// Round 6
// baseline (218.745 us; speedup 1.0000x reference)
//
#include <hip/hip_runtime.h>
#include <hip/hip_bf16.h>

#define H_DIM 768
#define E_DIM 128
#define NQ 64
#define LQ 32
#define ND 256
#define LD 180
#define QTOK (NQ*LQ)          // 2048
#define DTOK (ND*LD)          // 46080
#define TTOK (QTOK+DTOK)      // 48128

typedef __attribute__((ext_vector_type(8))) short short8;
typedef __attribute__((ext_vector_type(4))) float f32x4;
typedef __attribute__((ext_vector_type(4))) float float4v;

__device__ __forceinline__ unsigned short f2bf(float f) {
    union { float f; unsigned u; } v;
    v.f = f;
    unsigned r = v.u + 0x7fffu + ((v.u >> 16) & 1u);
    return (unsigned short)(r >> 16);
}

__device__ __forceinline__ void gl_lds16(const void* g, void* l) {
    __builtin_amdgcn_global_load_lds(
        (const __attribute__((address_space(1))) unsigned char*)g,
        (__attribute__((address_space(3))) unsigned char*)l, 16, 0, 0);
}

// ---------------------------------------------------------------------------
// prep: W1T/W2T bf16 transposes (write-coalesced), qcnt, and X -> xbf2 in
// MFMA fragment layout [16-row group][kb][ks][lhi][l15][8]. (proven r5)
// ---------------------------------------------------------------------------
__global__ __launch_bounds__(256) void prep_kernel(
    const float* __restrict__ qh, const float* __restrict__ dh,
    const float* __restrict__ W1, const float* __restrict__ W2,
    const int* __restrict__ qmask,
    unsigned short* __restrict__ W1T, unsigned short* __restrict__ W2T,
    float* __restrict__ qcnt, unsigned short* __restrict__ xbf2)
{
    int tid = blockIdx.x * 256 + threadIdx.x;
    int nth = gridDim.x * 256;
    for (int o = tid; o < H_DIM * H_DIM; o += nth) {
        int c = o / H_DIM, k = o - c * H_DIM;
        W1T[o] = f2bf(W1[(size_t)k * H_DIM + c]);
    }
    for (int o = tid; o < E_DIM * H_DIM; o += nth) {
        int c = o / H_DIM, k = o - c * H_DIM;
        W2T[o] = f2bf(W2[(size_t)k * E_DIM + c]);
    }
    if (tid < NQ) {
        int s = 0;
        for (int i = 0; i < LQ; ++i) s += qmask[tid * LQ + i];
        qcnt[tid] = (float)s;
    }
    if (xbf2) {
        const int NSLOT = (TTOK / 16) * 12 * 128;
        for (int S = tid; S < NSLOT; S += nth) {
            int sic = S & 127;
            int chunk = S >> 7;
            int kb = chunk % 12;
            int g  = chunk / 12;
            int ks  = sic >> 6;
            int lh2 = (sic >> 4) & 3;
            int L   = sic & 15;
            int row = g * 16 + L;
            int k0  = kb * 64 + ks * 32 + lh2 * 8;
            const float* src = (row < QTOK)
                ? (qh + (size_t)row * H_DIM + k0)
                : (dh + (size_t)(row - QTOK) * H_DIM + k0);
            float4v a = ((const float4v*)src)[0];
            float4v b = ((const float4v*)src)[1];
            union { unsigned short u[8]; short8 s8; } t;
            t.u[0] = f2bf(a.x); t.u[1] = f2bf(a.y); t.u[2] = f2bf(a.z); t.u[3] = f2bf(a.w);
            t.u[4] = f2bf(b.x); t.u[5] = f2bf(b.y); t.u[6] = f2bf(b.z); t.u[7] = f2bf(b.w);
            *(short8*)(xbf2 + (size_t)S * 8) = t.s8;
        }
    }
}

// ---------------------------------------------------------------------------
// head: BM=64, 4 waves (2Mx2N), BK=128. Proven 2-barrier schedule, halved
// step count: per jb = 6 A-steps (32 MFMA each) + 1 B-step (full W2 panel,
// 32 MFMA). afx fragments register-prefetched one step ahead (WAR reuse of
// the same registers — no extra VGPR).
// LDS 48KB: Bbuf 32K ([128 cols][128 k] bf16, swz) | T1 16K.
// ---------------------------------------------------------------------------
__global__ __launch_bounds__(256, 3) void head_kernel(
    const float* __restrict__ qh, const float* __restrict__ dh,
    const int* __restrict__ qmv, const int* __restrict__ dmv,
    const float* __restrict__ b1, const float* __restrict__ b2,
    const unsigned short* __restrict__ W1T, const unsigned short* __restrict__ W2T,
    unsigned short* __restrict__ emb, const unsigned short* __restrict__ xbf2)
{
    __shared__ char lds[49152];
    char* Bbuf = lds;            // 32K
    char* T1   = lds + 32768;    // 16K

    const int tid = threadIdx.x, lane = tid & 63, wv = tid >> 6;
    const int wm = wv >> 1, wn = wv & 1;
    const int l15 = lane & 15, lhi = lane >> 4;
    const int t0 = blockIdx.x * 64;
    const float* xsrc = (t0 < QTOK) ? (qh + (size_t)t0 * H_DIM)
                                    : (dh + (size_t)(t0 - QTOK) * H_DIM);

    // pre-swizzled source coords for Bbuf staging (linear LDS dest, rule 21)
    // dest o = i*4096 + wv*1024 + lane*16; col stride in LDS = 256B
    int bcol[8], bk[8];
    #pragma unroll
    for (int i = 0; i < 8; ++i) {
        int o = i * 4096 + wv * 1024 + lane * 16;
        int col = o >> 8;
        bcol[i] = col;
        bk[i] = ((o & 255) ^ ((col & 7) << 4)) >> 1;
    }

    #define STAGE_W1(JB, KB2) do {                                             \
        _Pragma("unroll")                                                      \
        for (int i_ = 0; i_ < 8; ++i_)                                         \
            gl_lds16(W1T + (size_t)((JB)*128 + bcol[i_]) * H_DIM + (KB2)*128 + bk[i_], \
                     Bbuf + i_*4096 + wv*1024);                                \
    } while (0)
    #define STAGE_W2(JB) do {                                                  \
        _Pragma("unroll")                                                      \
        for (int i_ = 0; i_ < 8; ++i_)                                         \
            gl_lds16(W2T + (size_t)bcol[i_] * H_DIM + (JB)*128 + bk[i_],       \
                     Bbuf + i_*4096 + wv*1024);                                \
    } while (0)

    const f32x4 zero4 = {0.f, 0.f, 0.f, 0.f};
    f32x4 eacc[2][4];
    #pragma unroll
    for (int mt = 0; mt < 2; ++mt)
        #pragma unroll
        for (int nt = 0; nt < 4; ++nt) eacc[mt][nt] = zero4;

    const size_t r16b = (size_t)(t0 >> 4);

    // afx fragments for the CURRENT kb2 step; prefetched one step ahead.
    short8 afx[2][4];
    if (xbf2) {
        #pragma unroll
        for (int mt = 0; mt < 2; ++mt)
            #pragma unroll
            for (int ks = 0; ks < 4; ++ks)
                afx[mt][ks] = *(const short8*)(xbf2 +
                    ((r16b + wm*2 + mt) * 24 + 0*4 + ks) * 512 + lhi*128 + l15*8);
    }

    #pragma unroll 1
    for (int jb = 0; jb < 6; ++jb) {
        f32x4 pacc[2][4];
        #pragma unroll
        for (int mt = 0; mt < 2; ++mt)
            #pragma unroll
            for (int nt = 0; nt < 4; ++nt) pacc[mt][nt] = zero4;

        #pragma unroll 1
        for (int kb2 = 0; kb2 < 6; ++kb2) {
            __syncthreads();              // previous step's Bbuf readers done
            STAGE_W1(jb, kb2);
            if (!xbf2) {
                // fallback: direct (uncoalesced) f32 loads for this step
                #pragma unroll
                for (int mt = 0; mt < 2; ++mt)
                    #pragma unroll
                    for (int ks = 0; ks < 4; ++ks) {
                        const float* p = xsrc + (size_t)(wm*32 + mt*16 + l15) * H_DIM + kb2*128 + ks*32 + lhi*8;
                        float4v a = ((const float4v*)p)[0], b = ((const float4v*)p)[1];
                        union { unsigned short u[8]; short8 s8; } tt;
                        tt.u[0]=f2bf(a.x); tt.u[1]=f2bf(a.y); tt.u[2]=f2bf(a.z); tt.u[3]=f2bf(a.w);
                        tt.u[4]=f2bf(b.x); tt.u[5]=f2bf(b.y); tt.u[6]=f2bf(b.z); tt.u[7]=f2bf(b.w);
                        afx[mt][ks] = tt.s8;
                    }
            }
            __syncthreads();              // stage drained

            const int nkb2 = (kb2 == 5) ? 0 : kb2 + 1;   // next step's afx chunk
            #pragma unroll
            for (int ks = 0; ks < 4; ++ks) {
                short8 bfr[4];
                #pragma unroll
                for (int nt = 0; nt < 4; ++nt) {
                    int col = wn * 64 + nt * 16 + l15;
                    int byte = (col * 256 + (ks * 32 + lhi * 8) * 2) ^ ((col & 7) << 4);
                    bfr[nt] = *(const short8*)(Bbuf + byte);
                }
                // swapped operands: pacc = T1^T fragment
                #pragma unroll
                for (int nt = 0; nt < 4; ++nt)
                    #pragma unroll
                    for (int mt = 0; mt < 2; ++mt)
                        pacc[mt][nt] = __builtin_amdgcn_mfma_f32_16x16x32_bf16(
                            bfr[nt], afx[mt][ks], pacc[mt][nt], 0, 0, 0);
                // prefetch next step's fragment into the just-freed registers
                if (xbf2) {
                    #pragma unroll
                    for (int mt = 0; mt < 2; ++mt)
                        afx[mt][ks] = *(const short8*)(xbf2 +
                            ((r16b + wm*2 + mt) * 24 + nkb2*4 + ks) * 512 + lhi*128 + l15*8);
                }
            }
        }

        // T1 write: bias+relu, 4 consecutive cols per b64 write
        #pragma unroll
        for (int mt = 0; mt < 2; ++mt) {
            int token = wm * 32 + mt * 16 + l15;
            int sw = (token & 7) << 4;
            #pragma unroll
            for (int nt = 0; nt < 4; ++nt) {
                int c0 = wn * 64 + nt * 16 + lhi * 4;
                union { unsigned short u[4]; unsigned long long q; } pk;
                #pragma unroll
                for (int r = 0; r < 4; ++r) {
                    float v = pacc[mt][nt][r] + b1[jb * 128 + c0 + r];
                    v = v > 0.f ? v : 0.f;
                    pk.u[r] = f2bf(v);
                }
                int byte = (token * 256 + c0 * 2) ^ sw;
                *(unsigned long long*)(T1 + byte) = pk.q;
            }
        }

        // phase B: eacc += T1 @ W2[jb-panel] — single full-panel stage
        __syncthreads();              // T1 visible; Bbuf readers done
        STAGE_W2(jb);
        __syncthreads();              // stage drained
        #pragma unroll
        for (int ks = 0; ks < 4; ++ks) {
            short8 at[2], bw[4];
            #pragma unroll
            for (int mt = 0; mt < 2; ++mt) {
                int row = wm * 32 + mt * 16 + l15;
                int byte = (row * 256 + (ks * 32 + lhi * 8) * 2) ^ ((row & 7) << 4);
                at[mt] = *(const short8*)(T1 + byte);
            }
            #pragma unroll
            for (int nt = 0; nt < 4; ++nt) {
                int col = wn * 64 + nt * 16 + l15;
                int byte = (col * 256 + (ks * 32 + lhi * 8) * 2) ^ ((col & 7) << 4);
                bw[nt] = *(const short8*)(Bbuf + byte);
            }
            #pragma unroll
            for (int mt = 0; mt < 2; ++mt)
                #pragma unroll
                for (int nt = 0; nt < 4; ++nt)
                    eacc[mt][nt] = __builtin_amdgcn_mfma_f32_16x16x32_bf16(
                        at[mt], bw[nt], eacc[mt][nt], 0, 0, 0);
        }
    }

    // epilogue: +b2, mask, L2-normalize, store bf16
    float* rs = (float*)lds;
    float b2v[4];
    #pragma unroll
    for (int nt = 0; nt < 4; ++nt) b2v[nt] = b2[wn*64 + nt*16 + l15];

    float vals[2][4][4], sq[2][4];
    #pragma unroll
    for (int mt = 0; mt < 2; ++mt)
        #pragma unroll
        for (int r = 0; r < 4; ++r) {
            int ri = mt*16 + lhi*4 + r;
            int t = t0 + wm*32 + ri;
            float fm = (float)((t < QTOK) ? qmv[t] : dmv[t - QTOK]);
            float s = 0.f;
            #pragma unroll
            for (int nt = 0; nt < 4; ++nt) {
                float v = (eacc[mt][nt][r] + b2v[nt]) * fm;
                vals[mt][nt][r] = v;
                s += v * v;
            }
            sq[mt][r] = s;
        }
    #pragma unroll
    for (int m1 = 1; m1 < 16; m1 <<= 1)
        #pragma unroll
        for (int mt = 0; mt < 2; ++mt)
            #pragma unroll
            for (int r = 0; r < 4; ++r)
                sq[mt][r] += __shfl_xor(sq[mt][r], m1, 64);
    __syncthreads();
    if (l15 == 0) {
        #pragma unroll
        for (int mt = 0; mt < 2; ++mt)
            #pragma unroll
            for (int r = 0; r < 4; ++r)
                rs[wv*32 + mt*16 + lhi*4 + r] = sq[mt][r];
    }
    __syncthreads();
    #pragma unroll
    for (int mt = 0; mt < 2; ++mt)
        #pragma unroll
        for (int r = 0; r < 4; ++r) {
            int ri = mt*16 + lhi*4 + r;
            float tot = rs[(wm*2)*32 + ri] + rs[(wm*2+1)*32 + ri];
            float sc = 1.f / fmaxf(sqrtf(tot), 1e-12f);
            int t = t0 + wm*32 + ri;
            #pragma unroll
            for (int nt = 0; nt < 4; ++nt)
                emb[(size_t)t * E_DIM + wn*64 + nt*16 + l15] = f2bf(vals[mt][nt][r] * sc);
        }
    #undef STAGE_W1
    #undef STAGE_W2
}

// ---------------------------------------------------------------------------
// score: block = (8-q group, d); qe persistent in regs; de staged in LDS.
// (unchanged — proven)
// ---------------------------------------------------------------------------
__global__ __launch_bounds__(256, 3) void score_kernel(
    const unsigned short* __restrict__ emb, const int* __restrict__ dmask,
    const float* __restrict__ qcnt, float* __restrict__ out)
{
    __shared__ char slds[16384 + 64];
    char* De = slds;
    float* red = (float*)(slds + 16384);

    const int d = blockIdx.x & 255;
    const int qg = blockIdx.x >> 8;
    const int tid = threadIdx.x, lane = tid & 63, wv = tid >> 6;
    const int l15 = lane & 15, lhi = lane >> 4;
    const int srow = tid >> 2, sseg = tid & 3;

    short8 af[4][4];
    #pragma unroll
    for (int mt = 0; mt < 4; ++mt)
        #pragma unroll
        for (int ks = 0; ks < 4; ++ks)
            af[mt][ks] = *(const short8*)(emb +
                (size_t)(qg*256 + wv*64 + mt*16 + l15) * E_DIM + ks*32 + lhi*8);

    float rmax[4][4];
    #pragma unroll
    for (int mt = 0; mt < 4; ++mt)
        #pragma unroll
        for (int r = 0; r < 4; ++r) rmax[mt][r] = -3.0e38f;

    const f32x4 zero4 = {0.f, 0.f, 0.f, 0.f};
    for (int ch = 0; ch < 3; ++ch) {
        int j = ch*64 + srow;
        int jv = (j < LD) ? j : 0;
        const unsigned short* src = emb + (size_t)(QTOK + d*LD + jv) * E_DIM + sseg*32;
        if (ch) __syncthreads();
        #pragma unroll
        for (int i = 0; i < 4; ++i) {
            short8 v = *(const short8*)(src + i*8);
            int byte = (srow * 256 + (sseg*32 + i*8) * 2) ^ ((srow & 7) << 4);
            *(short8*)(De + byte) = v;
        }
        __syncthreads();
        #pragma unroll
        for (int nt = 0; nt < 4; ++nt) {
            short8 bfr[4];
            int col = nt*16 + l15;
            #pragma unroll
            for (int ks = 0; ks < 4; ++ks) {
                int byte = (col * 256 + (ks*32 + lhi*8) * 2) ^ ((col & 7) << 4);
                bfr[ks] = *(const short8*)(De + byte);
            }
            f32x4 acc[4] = {zero4, zero4, zero4, zero4};
            #pragma unroll
            for (int ks = 0; ks < 4; ++ks)
                #pragma unroll
                for (int mt = 0; mt < 4; ++mt)
                    acc[mt] = __builtin_amdgcn_mfma_f32_16x16x32_bf16(
                        af[mt][ks], bfr[ks], acc[mt], 0, 0, 0);
            int jcol = ch*64 + nt*16 + l15;
            float mval = (jcol < LD) ? (float)dmask[d*LD + jcol] : -1.f;
            #pragma unroll
            for (int mt = 0; mt < 4; ++mt)
                #pragma unroll
                for (int r = 0; r < 4; ++r) {
                    float v = (mval < 0.f) ? -3.0e38f : acc[mt][r] * mval;
                    rmax[mt][r] = fmaxf(rmax[mt][r], v);
                }
        }
    }
    #pragma unroll
    for (int m1 = 1; m1 < 16; m1 <<= 1)
        #pragma unroll
        for (int mt = 0; mt < 4; ++mt)
            #pragma unroll
            for (int r = 0; r < 4; ++r)
                rmax[mt][r] = fmaxf(rmax[mt][r], __shfl_xor(rmax[mt][r], m1, 64));
    float s0 = 0.f, s1 = 0.f;
    #pragma unroll
    for (int r = 0; r < 4; ++r) { s0 += rmax[0][r] + rmax[1][r]; s1 += rmax[2][r] + rmax[3][r]; }
    s0 += __shfl_xor(s0, 16, 64); s0 += __shfl_xor(s0, 32, 64);
    s1 += __shfl_xor(s1, 16, 64); s1 += __shfl_xor(s1, 32, 64);
    if (lane == 0) { red[wv*2 + 0] = s0; red[wv*2 + 1] = s1; }
    __syncthreads();
    if (tid < 8) {
        int q = qg*8 + tid;
        out[q * ND + d] = red[tid] / qcnt[q];
    }
}

extern "C" void kernel_launch(void* const* d_in, const int* in_sizes, int n_in,
                              void* d_out, int out_size, void* d_ws, size_t ws_size,
                              hipStream_t stream)
{
    const float* qh = (const float*)d_in[0];
    const float* dh = (const float*)d_in[1];
    const int*   qm = (const int*)d_in[2];
    const int*   dm = (const int*)d_in[3];
    const float* W1 = (const float*)d_in[4];
    const float* b1 = (const float*)d_in[5];
    const float* W2 = (const float*)d_in[6];
    const float* b2 = (const float*)d_in[7];
    float* out = (float*)d_out;

    unsigned short* emb = (unsigned short*)d_ws;                  // [48128][128] bf16
    unsigned short* W1T = emb + (size_t)TTOK * E_DIM;             // [768][768]
    unsigned short* W2T = W1T + (size_t)H_DIM * H_DIM;            // [128][768]
    float* qcnt = (float*)(W2T + (size_t)E_DIM * H_DIM);          // [64]
    size_t base_need = (size_t)TTOK*E_DIM*2 + (size_t)H_DIM*H_DIM*2
                     + (size_t)E_DIM*H_DIM*2 + 256;
    size_t xbf_need = (size_t)TTOK * H_DIM * 2;
    unsigned short* xbf2 = nullptr;
    if (ws_size >= base_need + xbf_need)
        xbf2 = (unsigned short*)((char*)d_ws + base_need);

    prep_kernel<<<2048, 256, 0, stream>>>(qh, dh, W1, W2, qm, W1T, W2T, qcnt, xbf2);
    head_kernel<<<TTOK / 64, 256, 0, stream>>>(qh, dh, qm, dm, b1, b2, W1T, W2T, emb, xbf2);
    score_kernel<<<8 * ND, 256, 0, stream>>>(emb, dm, qcnt, out);
}